// Round 9
// baseline (233.467 us; speedup 1.0000x reference)
//
#include <hip/hip_runtime.h>
#include <math.h>

// Problem constants (fixed by the reference)
constexpr int Bn = 16;    // batch
constexpr int Cn = 256;   // in channels
constexpr int Mn = 128;   // med channels
constexpr int Nn = 4096;  // H*W

typedef short bf16x8 __attribute__((ext_vector_type(8)));     // 8 bf16 (4 VGPRs)
typedef float f32x4 __attribute__((ext_vector_type(4)));      // MFMA accum
typedef unsigned short us8 __attribute__((ext_vector_type(8)));
typedef unsigned short us4 __attribute__((ext_vector_type(4)));

static __device__ __forceinline__ unsigned short f2bf(float f) {
  union { float f; unsigned int u; } c{f};
  unsigned int u = c.u;
  u += 0x7FFFu + ((u >> 16) & 1u);   // RNE
  return (unsigned short)(u >> 16);
}

// Direct global->LDS 16B copy (dest must be wave-uniform base + lane*16).
static __device__ __forceinline__ void gload_lds16(const void* g, void* l) {
  __builtin_amdgcn_global_load_lds(
      (const __attribute__((address_space(1))) unsigned int*)g,
      (__attribute__((address_space(3))) unsigned int*)l, 16, 0, 0);
}

// ---------------------------------------------------------------------------
// P1 (merged prep): xT[b][n][c] bf16 = transpose+cast of x[b][c][n].
// Blocks with (y==0 && z==0) additionally prepare the weights:
//   Wv[128][256] bf16 (k-contig rows of w_v),
//   woT[256][128] bf16 = transpose of w_o (m-contig rows for k_ww),
//   and zero rs (atomic target of k_proj_v).
// ---------------------------------------------------------------------------
__global__ __launch_bounds__(256) void k_prep(
    const float* __restrict__ x, unsigned short* __restrict__ xT,
    const float* __restrict__ w_o, const float* __restrict__ w_v,
    unsigned short* __restrict__ Wv, unsigned short* __restrict__ woT,
    float* __restrict__ rs) {
  const int b = blockIdx.z;
  const int c0 = blockIdx.y * 128;
  const int n0 = blockIdx.x * 64;
  const int t = threadIdx.x;

  if (blockIdx.y == 0 && blockIdx.z == 0) {   // weight prep rides on 64 blocks
    int idx = blockIdx.x * 256 + t;           // 0..16383
    if (idx < Bn * Mn) rs[idx] = 0.f;
    if (idx < 8192) {             // Wv: 128x256, 4 c-contig per thread
      int row = idx >> 6;
      int c4 = (idx & 63) * 4;
      float4 f = *(const float4*)&w_v[(size_t)row * Cn + c4];
      us4 g = {f2bf(f.x), f2bf(f.y), f2bf(f.z), f2bf(f.w)};
      *(us4*)&Wv[(size_t)row * Cn + c4] = g;
    } else {                      // woT: 256x128, 4 m-contig per thread
      int j = idx - 8192;
      int cp = j >> 5;            // 0..255
      int m4 = (j & 31) * 4;      // 0..124
      us4 g;
#pragma unroll
      for (int e = 0; e < 4; ++e) g[e] = f2bf(w_o[(size_t)(m4 + e) * Cn + cp]);
      *(us4*)&woT[(size_t)cp * Mn + m4] = g;
    }
  }

  const int n4 = (t & 15) * 4;          // 0..60
  const int c8 = c0 + (t >> 4) * 8;     // 8 consecutive c per thread
  const float* xb = x + ((size_t)b * Cn + c8) * Nn + n0 + n4;
  float4 r[8];
#pragma unroll
  for (int i = 0; i < 8; ++i) r[i] = *(const float4*)&xb[(size_t)i * Nn];
  unsigned short* dst = xT + ((size_t)b * Nn + n0 + n4) * Cn + c8;
#pragma unroll
  for (int j = 0; j < 4; ++j) {
    us8 g;
#pragma unroll
    for (int i = 0; i < 8; ++i) g[i] = f2bf(((const float*)&r[i])[j]);
    *(us8*)&dst[(size_t)j * Cn] = g;
  }
}

// ---------------------------------------------------------------------------
// K1 (MFMA): v-projection + fused softmax Gram, 64-n tiles.
// Grid 64x16 = 1024 blocks; LDS 33 KB -> 4 blocks/CU capacity (occupancy was
// grid-capped at 2/CU with 128-n tiles). Pipelined K-loop: Wv staged via
// global_load_lds w=16; xT reg-prefetched one 64-K tile ahead. v[m][n]
// (128m x 64n) stays in registers. Max-free softmax stats: cs[n] block-local
// (block covers all 128 m); rs[m] partials atomicAdd'd. Utilde =
// exp(v)*rsqrt(cs) hi/lo-bf16 staged to XOR-granule LDS (single pass — U
// fits 32 KB); Gram partial G = U^T U (hi*hi+hi*lo+lo*hi on the matrix pipe)
// written to Ap[nt] (fp32, summed by k_reduceA).
// ---------------------------------------------------------------------------
__global__ __launch_bounds__(256) void k_proj_v(
    const unsigned short* __restrict__ Wv,
    const unsigned short* __restrict__ xT,
    const float* __restrict__ b_v,
    float* __restrict__ Ap, float* __restrict__ rs) {
  __shared__ us8 pool[2 * 8 * 128];    // 32 KB: K staging (24 KB) / Gram H+L
  __shared__ float cs_lds[2][64];      // column-sum partials (two m-halves)
  unsigned short* ldsA = (unsigned short*)pool;              // Wv tile 16 KB
  unsigned short* ldsB = (unsigned short*)pool + 8 * 128 * 8; // x tile 8 KB
  const int b = blockIdx.y;
  const int nt = blockIdx.x;           // 64-n tile index
  const int t = threadIdx.x;
  const int wave = t >> 6, lane = t & 63;
  const int quad = lane >> 4, l16 = lane & 15;
  const int wm = (wave & 1) * 64;      // m-offset (K-phase and Gram rows)
  const int wn = (wave >> 1) * 32;     // n-offset (K-phase)
  const int wk = (wave >> 1) * 64;     // k-offset (Gram cols)
  f32x4 acc[4][4] = {};                // K-phase uses [i][0..1]; Gram all
  const unsigned short* xb = xT + ((size_t)b * Nn + nt * 64) * Cn;

  uint4 rB[2];                         // x-tile prefetch (512 granules, 2/thr)
#pragma unroll
  for (int p = 0; p < 2; ++p) {
    int s = p * 256 + t;               // row = s&63, g = s>>6
    rB[p] = *(const uint4*)&xb[(size_t)(s & 63) * Cn + (s >> 6) * 8];
  }

  for (int k0 = 0; k0 < Cn; k0 += 64) {
#pragma unroll
    for (int p = 0; p < 2; ++p) {      // x-tile: 512 granules
      int s = p * 256 + t;
      *(uint4*)&ldsB[(size_t)s * 8] = rB[p];
    }
#pragma unroll
    for (int p = 0; p < 4; ++p) {      // Wv tile: 1024 granules via gload_lds
      int s = p * 256 + t;             // row = s&127, g = s>>7
      gload_lds16(&Wv[(size_t)(s & 127) * Cn + k0 + (s >> 7) * 8],
                  &ldsA[(size_t)s * 8]);
    }
    __syncthreads();
    if (k0 + 64 < Cn) {                // issue next x tile early
#pragma unroll
      for (int p = 0; p < 2; ++p) {
        int s = p * 256 + t;
        rB[p] = *(const uint4*)&xb[(size_t)(s & 63) * Cn + k0 + 64 + (s >> 6) * 8];
      }
    }
#pragma unroll
    for (int ss = 0; ss < 2; ++ss) {   // two k-steps of 32
      int g4 = ss * 4 + quad;
      bf16x8 af[4], bfr[2];
#pragma unroll
      for (int i = 0; i < 4; ++i)
        af[i] = *(const bf16x8*)&ldsA[(size_t)(g4 * 128 + wm + i * 16 + l16) * 8];
#pragma unroll
      for (int j = 0; j < 2; ++j)
        bfr[j] = *(const bf16x8*)&ldsB[(size_t)(g4 * 64 + wn + j * 16 + l16) * 8];
#pragma unroll
      for (int i = 0; i < 4; ++i)
#pragma unroll
        for (int j = 0; j < 2; ++j)
          acc[i][j] = __builtin_amdgcn_mfma_f32_16x16x32_bf16(af[i], bfr[j], acc[i][j], 0, 0, 0);
    }
    __syncthreads();
  }

  // ---- e = exp(v + b_v) in place (j<2 columns live) ----
#pragma unroll
  for (int i = 0; i < 4; ++i) {
#pragma unroll
    for (int r = 0; r < 4; ++r) {
      float bi = b_v[wm + i * 16 + quad * 4 + r];
#pragma unroll
      for (int j = 0; j < 2; ++j)
        acc[i][j][r] = __expf(acc[i][j][r] + bi);
    }
  }

  // Row-sum partials (over this block's 64 n) -> atomicAdd rs[b,m]
#pragma unroll
  for (int i = 0; i < 4; ++i) {
#pragma unroll
    for (int r = 0; r < 4; ++r) {
      float s = acc[i][0][r] + acc[i][1][r];
      s += __shfl_xor(s, 1); s += __shfl_xor(s, 2);
      s += __shfl_xor(s, 4); s += __shfl_xor(s, 8);
      if (l16 == 0)
        atomicAdd(&rs[b * Mn + wm + i * 16 + quad * 4 + r], s);
    }
  }

  // Column sums cs[n] over ALL 128 m (block-local): quad-reduce within wave
  // gives this wave's 64-m partial; LDS combines the two m-halves.
  float csj[2];
#pragma unroll
  for (int j = 0; j < 2; ++j) {
    float c = 0.f;
#pragma unroll
    for (int i = 0; i < 4; ++i)
#pragma unroll
      for (int r = 0; r < 4; ++r) c += acc[i][j][r];
    c += __shfl_xor(c, 16);
    c += __shfl_xor(c, 32);
    csj[j] = c;
  }
  if (quad == 0) {
#pragma unroll
    for (int j = 0; j < 2; ++j) cs_lds[wave & 1][wn + j * 16 + l16] = csj[j];
  }
  __syncthreads();   // also: K-loop LDS reads done -> safe to overwrite pool

  float rinv[2];
#pragma unroll
  for (int j = 0; j < 2; ++j) {
    int nl = wn + j * 16 + l16;
    rinv[j] = rsqrtf(cs_lds[0][nl] + cs_lds[1][nl]);
  }

  // Stage Utilde hi/lo into XOR-granule LDS: granule gl = n/8 (8 of them),
  // slot = gl*128 + (m^gl), halfword = n&7. Single pass (64n x 128m fits).
  unsigned short* Hs = (unsigned short*)pool;            // 16 KB (8*128 us8)
  unsigned short* Ls = Hs + 8 * 128 * 8;                 // 16 KB
#pragma unroll
  for (int i = 0; i < 4; ++i) {
#pragma unroll
    for (int r = 0; r < 4; ++r) {
      int m = wm + i * 16 + quad * 4 + r;
#pragma unroll
      for (int j = 0; j < 2; ++j) {
        int nl = wn + j * 16 + l16;
        float u = acc[i][j][r] * rinv[j];
        unsigned short h = f2bf(u);
        union { unsigned int q; float f; } hf{(unsigned int)h << 16};
        int idx = ((nl >> 3) * 128 + (m ^ (nl >> 3))) * 8 + (nl & 7);
        Hs[idx] = h;
        Ls[idx] = f2bf(u - hf.f);
      }
    }
  }
  __syncthreads();

  // Gram MFMA: G[m][k] += sum_n U[n][m]*U[n][k], hi/lo 3-product scheme.
  const bf16x8* Hv = (const bf16x8*)pool;
  const bf16x8* Lv = Hv + 8 * 128;
#pragma unroll
  for (int i = 0; i < 4; ++i)
#pragma unroll
    for (int j = 0; j < 4; ++j) acc[i][j] = (f32x4){0.f, 0.f, 0.f, 0.f};
#pragma unroll
  for (int ss = 0; ss < 2; ++ss) {     // contraction = 64 n = 2 k-steps
    int g = ss * 4 + quad;
    bf16x8 hA[4], lA[4], hB[4], lB[4];
#pragma unroll
    for (int i = 0; i < 4; ++i) {
      int mi = wm + i * 16 + l16;
      int ki = wk + i * 16 + l16;
      hA[i] = Hv[g * 128 + (mi ^ g)];
      lA[i] = Lv[g * 128 + (mi ^ g)];
      hB[i] = Hv[g * 128 + (ki ^ g)];
      lB[i] = Lv[g * 128 + (ki ^ g)];
    }
#pragma unroll
    for (int i = 0; i < 4; ++i)
#pragma unroll
      for (int j = 0; j < 4; ++j) {
        acc[i][j] = __builtin_amdgcn_mfma_f32_16x16x32_bf16(hA[i], hB[j], acc[i][j], 0, 0, 0);
        acc[i][j] = __builtin_amdgcn_mfma_f32_16x16x32_bf16(hA[i], lB[j], acc[i][j], 0, 0, 0);
        acc[i][j] = __builtin_amdgcn_mfma_f32_16x16x32_bf16(lA[i], hB[j], acc[i][j], 0, 0, 0);
      }
  }

  float* Apb = Ap + ((size_t)nt * Bn + b) * (Mn * Mn);
#pragma unroll
  for (int i = 0; i < 4; ++i) {
#pragma unroll
    for (int r = 0; r < 4; ++r) {
      int m = wm + i * 16 + quad * 4 + r;
      float* row = &Apb[(size_t)m * Mn];
#pragma unroll
      for (int j = 0; j < 4; ++j)
        row[wk + j * 16 + l16] = acc[i][j][r];
    }
  }
}

// ---------------------------------------------------------------------------
// K2: A[b][m][k] = (1/rs[b][m]) * sum_s Ap[s][b][m][k]
// ---------------------------------------------------------------------------
__global__ __launch_bounds__(256) void k_reduceA(
    const float* __restrict__ Ap, const float* __restrict__ rs,
    float* __restrict__ A, int S) {
  int tid = blockIdx.x * 256 + threadIdx.x;           // over Bn*Mn*Mn/4
  int idx4 = tid * 4;
  int b = idx4 / (Mn * Mn);
  int off = idx4 - b * (Mn * Mn);
  float4 s = {0.f, 0.f, 0.f, 0.f};
  for (int s0 = 0; s0 < S; ++s0) {
    float4 p = *(const float4*)&Ap[((size_t)s0 * Bn + b) * (Mn * Mn) + off];
    s.x += p.x; s.y += p.y; s.z += p.z; s.w += p.w;
  }
  float sc = 1.0f / rs[b * Mn + (off >> 7)];   // row m scale
  s.x *= sc; s.y *= sc; s.z *= sc; s.w *= sc;
  *(float4*)&A[idx4] = s;
}

// ---------------------------------------------------------------------------
// K3: W2bf[b,c,m] = bf16( sum_k w_c[c,k] * A[b,m,k] )  (m-contiguous)
// ---------------------------------------------------------------------------
__global__ __launch_bounds__(256) void k_w2(
    const float* __restrict__ w_c, const float* __restrict__ A,
    unsigned short* __restrict__ W2bf) {
  __shared__ float As[64][68];   // [k][m-local]
  __shared__ float wcs[64][68];  // [k][c-local]
  const int b = blockIdx.z;
  const int m0 = blockIdx.x * 64;
  const int c0 = blockIdx.y * 64;
  const int t = threadIdx.x;
  const int tc = (t >> 4) * 4, tmm = (t & 15) * 4;
  float acc[4][4] = {};
  for (int k0 = 0; k0 < Mn; k0 += 64) {
    int r = t >> 2;             // 0..63
    int k4 = (t & 3) * 4;
#pragma unroll
    for (int p = 0; p < 4; ++p) {
      int k = k4 + p * 16;
      float4 a4 = *(const float4*)&A[((size_t)(b * Mn + m0 + r)) * Mn + k0 + k];
      As[k + 0][r] = a4.x; As[k + 1][r] = a4.y; As[k + 2][r] = a4.z; As[k + 3][r] = a4.w;
      float4 w4 = *(const float4*)&w_c[(size_t)(c0 + r) * Mn + k0 + k];
      wcs[k + 0][r] = w4.x; wcs[k + 1][r] = w4.y; wcs[k + 2][r] = w4.z; wcs[k + 3][r] = w4.w;
    }
    __syncthreads();
#pragma unroll
    for (int kk = 0; kk < 64; ++kk) {
      float4 w4 = *(const float4*)&wcs[kk][tc];
      float4 a4 = *(const float4*)&As[kk][tmm];
      float w[4] = {w4.x, w4.y, w4.z, w4.w};
      float a[4] = {a4.x, a4.y, a4.z, a4.w};
#pragma unroll
      for (int i = 0; i < 4; ++i)
#pragma unroll
        for (int jj = 0; jj < 4; ++jj) acc[i][jj] = fmaf(w[i], a[jj], acc[i][jj]);
    }
    __syncthreads();
  }
#pragma unroll
  for (int i = 0; i < 4; ++i) {
    us4 g4 = {f2bf(acc[i][0]), f2bf(acc[i][1]), f2bf(acc[i][2]), f2bf(acc[i][3])};
    *(us4*)&W2bf[((size_t)(b * Cn + c0 + tc + i)) * Mn + m0 + tmm] = g4;
  }
}

// ---------------------------------------------------------------------------
// K4 (MFMA): WW[b][c][c'] = bf16( sum_m W2bf[b,c,m] * woT[c',m] )  (= W2*W_o)
// Also (c'-tile 0 blocks): bb[b][c] = sum_m W2[c,m]*b_o[m] + b_c[c].
// ---------------------------------------------------------------------------
__global__ __launch_bounds__(256) void k_ww(
    const unsigned short* __restrict__ W2bf, const unsigned short* __restrict__ woT,
    const float* __restrict__ b_o, const float* __restrict__ b_c,
    unsigned short* __restrict__ WW, float* __restrict__ bb) {
  __shared__ us8 ldsA[128 * 16];  // 32 KB: W2 c-rows   [row][granule^]
  __shared__ us8 ldsB[128 * 16];  // 32 KB: woT c'-rows
  __shared__ float bo_lds[128];
  const int b = blockIdx.z;
  const int c_t = blockIdx.y * 128;
  const int cp_t = blockIdx.x * 128;
  const int t = threadIdx.x;
  const int wave = t >> 6, lane = t & 63;
  const int quad = lane >> 4, l16 = lane & 15;
  const int wc = (wave & 1) * 64, wp = (wave >> 1) * 64;
  const unsigned short* W2b = W2bf + ((size_t)b * Cn + c_t) * Mn;
  const unsigned short* woB = woT + (size_t)cp_t * Mn;

#pragma unroll
  for (int p = 0; p < 8; ++p) {
    int s = p * 256 + t;
    int row = s >> 4, g = s & 15;
    int slot = row * 16 + (g ^ (row & 15));
    ldsA[slot] = *(const us8*)&W2b[(size_t)row * Mn + g * 8];
    ldsB[slot] = *(const us8*)&woB[(size_t)row * Mn + g * 8];
  }
  if (blockIdx.x == 0 && t < 128) bo_lds[t] = b_o[t];
  __syncthreads();

  f32x4 acc[4][4] = {};
#pragma unroll
  for (int s = 0; s < 4; ++s) {
    int gq = s * 4 + quad;
    int xo = gq ^ l16;
    bf16x8 af[4], bfr[4];
#pragma unroll
    for (int i = 0; i < 4; ++i)
      af[i] = *(const bf16x8*)&ldsA[(wc + i * 16 + l16) * 16 + xo];
#pragma unroll
    for (int j = 0; j < 4; ++j)
      bfr[j] = *(const bf16x8*)&ldsB[(wp + j * 16 + l16) * 16 + xo];
#pragma unroll
    for (int i = 0; i < 4; ++i)
#pragma unroll
      for (int j = 0; j < 4; ++j)
        acc[i][j] = __builtin_amdgcn_mfma_f32_16x16x32_bf16(af[i], bfr[j], acc[i][j], 0, 0, 0);
  }

#pragma unroll
  for (int i = 0; i < 4; ++i) {
#pragma unroll
    for (int r = 0; r < 4; ++r) {
      int c = c_t + wc + i * 16 + quad * 4 + r;
      unsigned short* row = &WW[((size_t)b * Cn + c) * Cn + cp_t];
#pragma unroll
      for (int j = 0; j < 4; ++j)
        row[wp + j * 16 + l16] = f2bf(acc[i][j][r]);
    }
  }

  if (blockIdx.x == 0 && t < 128) {   // bias: dot(W2[c,:], b_o) + b_c
    float s = 0.f;
#pragma unroll
    for (int g = 0; g < 16; ++g) {
      us8 h = ldsA[t * 16 + (g ^ (t & 15))];
#pragma unroll
      for (int e = 0; e < 8; ++e) {
        union { unsigned int u; float f; } cv{(unsigned int)h[e] << 16};
        s = fmaf(cv.f, bo_lds[g * 8 + e], s);
      }
    }
    bb[b * Cn + c_t + t] = s + b_c[c_t + t];
  }
}

// ---------------------------------------------------------------------------
// K5 (MFMA): out[b,c,n] = gamma*relu(sum_{c'} WW[c,c']*xT[n,c'] + bb[c]) + x
// Tile 128c x 128n, K=256 in two staged halves. Staging via global_load_lds
// w=16 with PRE-SWIZZLED global source (granule g' = g ^ (row&15)) so the
// LDS dest stays linear while reads keep the proven XOR layout (2-way free).
// XCD-aware bijective block swizzle: each XCD gets 2 contiguous batches so
// its 4 MB L2 holds that batch-pair's xT panels + WW.
// ---------------------------------------------------------------------------
__global__ __launch_bounds__(256) void k_final_mfma(
    const unsigned short* __restrict__ WW, const unsigned short* __restrict__ xT,
    const float* __restrict__ x, const float* __restrict__ bb,
    const float* __restrict__ gamma, float* __restrict__ out) {
  __shared__ us8 ldsA[128 * 16];  // 32 KB: WW c-rows (one K-half)
  __shared__ us8 ldsB[128 * 16];  // 32 KB: xT n-rows
  // flat grid = 32 x 2 x 16 = 1024; 1024 % 8 == 0 -> simple bijective swizzle
  const int flat = blockIdx.x + 32 * blockIdx.y + 64 * (int)blockIdx.z;
  const int swz = (flat & 7) * 128 + (flat >> 3);
  const int n_t = (swz & 31) * 128;
  const int c_t = ((swz >> 5) & 1) * 128;
  const int b = swz >> 6;
  const int t = threadIdx.x;
  const int wave = t >> 6, lane = t & 63;
  const int quad = lane >> 4, l16 = lane & 15;
  const int wc = (wave & 1) * 64, wn = (wave >> 1) * 64;
  const unsigned short* WWb = WW + ((size_t)b * Cn + c_t) * Cn;
  const unsigned short* xTb = xT + ((size_t)b * Nn + n_t) * Cn;
  unsigned short* ldsAu = (unsigned short*)ldsA;
  unsigned short* ldsBu = (unsigned short*)ldsB;

  f32x4 acc[4][4] = {};
  for (int k0 = 0; k0 < Cn; k0 += 128) {
#pragma unroll
    for (int p = 0; p < 8; ++p) {   // 2048 granules per operand, 8/thread
      int s = p * 256 + t;
      int row = s >> 4, g = s & 15;
      int gsw = g ^ (row & 15);     // pre-swizzled source granule
      gload_lds16(&WWb[(size_t)row * Cn + k0 + gsw * 8], &ldsAu[(size_t)s * 8]);
      gload_lds16(&xTb[(size_t)row * Cn + k0 + gsw * 8], &ldsBu[(size_t)s * 8]);
    }
    __syncthreads();
#pragma unroll
    for (int s = 0; s < 4; ++s) {
      int gq = s * 4 + quad;
      int xo = gq ^ l16;
      bf16x8 af[4], bfr[4];
#pragma unroll
      for (int i = 0; i < 4; ++i)
        af[i] = *(const bf16x8*)&ldsA[(wc + i * 16 + l16) * 16 + xo];
#pragma unroll
      for (int j = 0; j < 4; ++j)
        bfr[j] = *(const bf16x8*)&ldsB[(wn + j * 16 + l16) * 16 + xo];
#pragma unroll
      for (int i = 0; i < 4; ++i)
#pragma unroll
        for (int j = 0; j < 4; ++j)
          acc[i][j] = __builtin_amdgcn_mfma_f32_16x16x32_bf16(af[i], bfr[j], acc[i][j], 0, 0, 0);
    }
    __syncthreads();
  }

  float g = gamma[0];
#pragma unroll
  for (int i = 0; i < 4; ++i) {
#pragma unroll
    for (int r = 0; r < 4; ++r) {
      int c = c_t + wc + i * 16 + quad * 4 + r;
      float bias = bb[b * Cn + c];
      const float* xr = &x[((size_t)b * Cn + c) * Nn + n_t];
      float* orow = &out[((size_t)b * Cn + c) * Nn + n_t];
#pragma unroll
      for (int j = 0; j < 4; ++j) {
        int n = wn + j * 16 + l16;
        orow[n] = g * fmaxf(acc[i][j][r] + bias, 0.f) + xr[n];
      }
    }
  }
}

// ---------------------------------------------------------------------------
extern "C" void kernel_launch(void* const* d_in, const int* in_sizes, int n_in,
                              void* d_out, int out_size, void* d_ws, size_t ws_size,
                              hipStream_t stream) {
  const float* x   = (const float*)d_in[0];
  const float* w_o = (const float*)d_in[1];
  const float* b_o = (const float*)d_in[2];
  const float* w_v = (const float*)d_in[3];
  const float* b_v = (const float*)d_in[4];
  const float* w_c = (const float*)d_in[5];
  const float* b_c = (const float*)d_in[6];
  const float* gm  = (const float*)d_in[7];

  constexpr int S = Nn / 64;                       // 64 Gram slices
  float* ws = (float*)d_ws;
  float* rs = ws;                                  // B*M fp32 (atomic)
  float* bb = rs + Bn * Mn;                        // B*C fp32
  float* A  = bb + Bn * Cn;                        // B*M*M fp32
  float* Ap = A + (size_t)Bn * Mn * Mn;            // S*B*M*M fp32
  unsigned short* WW   = (unsigned short*)(Ap + (size_t)S * Bn * Mn * Mn); // B*C*C bf16
  unsigned short* W2bf = WW + (size_t)Bn * Cn * Cn;                 // B*C*M bf16
  unsigned short* xT   = W2bf + (size_t)Bn * Cn * Mn;               // B*N*C bf16
  unsigned short* Wv   = xT + (size_t)Bn * Nn * Cn;                 // M*C bf16
  unsigned short* woT  = Wv + (size_t)Mn * Cn;                      // C*M bf16

  k_prep<<<dim3(Nn / 64, 2, Bn), 256, 0, stream>>>(x, xT, w_o, w_v, Wv, woT, rs);
  k_proj_v<<<dim3(Nn / 64, Bn), 256, 0, stream>>>(Wv, xT, b_v, Ap, rs);
  k_reduceA<<<dim3(Bn * Mn * Mn / 1024), 256, 0, stream>>>(Ap, rs, A, S);
  k_w2<<<dim3(Mn / 64, Cn / 64, Bn), 256, 0, stream>>>(w_c, A, W2bf);
  k_ww<<<dim3(2, 2, Bn), 256, 0, stream>>>(W2bf, woT, b_o, b_c, WW, bb);
  k_final_mfma<<<dim3(Nn / 128, Cn / 128, Bn), 256, 0, stream>>>(WW, xT, x, bb, gm, (float*)d_out);
}

// Round 10
// 202.962 us; speedup vs baseline: 1.1503x; 1.1503x over previous
//
#include <hip/hip_runtime.h>
#include <math.h>

// Problem constants (fixed by the reference)
constexpr int Bn = 16;    // batch
constexpr int Cn = 256;   // in channels
constexpr int Mn = 128;   // med channels
constexpr int Nn = 4096;  // H*W

typedef short bf16x8 __attribute__((ext_vector_type(8)));     // 8 bf16 (4 VGPRs)
typedef float f32x4 __attribute__((ext_vector_type(4)));      // MFMA accum
typedef unsigned short us8 __attribute__((ext_vector_type(8)));
typedef unsigned short us4 __attribute__((ext_vector_type(4)));

static __device__ __forceinline__ unsigned short f2bf(float f) {
  union { float f; unsigned int u; } c{f};
  unsigned int u = c.u;
  u += 0x7FFFu + ((u >> 16) & 1u);   // RNE
  return (unsigned short)(u >> 16);
}

// Direct global->LDS 16B copy (dest must be wave-uniform base + lane*16).
static __device__ __forceinline__ void gload_lds16(const void* g, void* l) {
  __builtin_amdgcn_global_load_lds(
      (const __attribute__((address_space(1))) unsigned int*)g,
      (__attribute__((address_space(3))) unsigned int*)l, 16, 0, 0);
}

// ---------------------------------------------------------------------------
// P1 (merged prep): xT[b][n][c] bf16 = transpose+cast of x[b][c][n].
// Blocks with (y==0 && z==0) additionally prepare the weights:
//   Wv[128][256] bf16 (k-contig rows of w_v),
//   woT[256][128] bf16 = transpose of w_o (m-contig rows for k_ww),
//   and zero rs (atomic target of k_proj_v).
// ---------------------------------------------------------------------------
__global__ __launch_bounds__(256) void k_prep(
    const float* __restrict__ x, unsigned short* __restrict__ xT,
    const float* __restrict__ w_o, const float* __restrict__ w_v,
    unsigned short* __restrict__ Wv, unsigned short* __restrict__ woT,
    float* __restrict__ rs) {
  const int b = blockIdx.z;
  const int c0 = blockIdx.y * 128;
  const int n0 = blockIdx.x * 64;
  const int t = threadIdx.x;

  if (blockIdx.y == 0 && blockIdx.z == 0) {   // weight prep rides on 64 blocks
    int idx = blockIdx.x * 256 + t;           // 0..16383
    if (idx < Bn * Mn) rs[idx] = 0.f;
    if (idx < 8192) {             // Wv: 128x256, 4 c-contig per thread
      int row = idx >> 6;
      int c4 = (idx & 63) * 4;
      float4 f = *(const float4*)&w_v[(size_t)row * Cn + c4];
      us4 g = {f2bf(f.x), f2bf(f.y), f2bf(f.z), f2bf(f.w)};
      *(us4*)&Wv[(size_t)row * Cn + c4] = g;
    } else {                      // woT: 256x128, 4 m-contig per thread
      int j = idx - 8192;
      int cp = j >> 5;            // 0..255
      int m4 = (j & 31) * 4;      // 0..124
      us4 g;
#pragma unroll
      for (int e = 0; e < 4; ++e) g[e] = f2bf(w_o[(size_t)(m4 + e) * Cn + cp]);
      *(us4*)&woT[(size_t)cp * Mn + m4] = g;
    }
  }

  const int n4 = (t & 15) * 4;          // 0..60
  const int c8 = c0 + (t >> 4) * 8;     // 8 consecutive c per thread
  const float* xb = x + ((size_t)b * Cn + c8) * Nn + n0 + n4;
  float4 r[8];
#pragma unroll
  for (int i = 0; i < 8; ++i) r[i] = *(const float4*)&xb[(size_t)i * Nn];
  unsigned short* dst = xT + ((size_t)b * Nn + n0 + n4) * Cn + c8;
#pragma unroll
  for (int j = 0; j < 4; ++j) {
    us8 g;
#pragma unroll
    for (int i = 0; i < 8; ++i) g[i] = f2bf(((const float*)&r[i])[j]);
    *(us8*)&dst[(size_t)j * Cn] = g;
  }
}

// ---------------------------------------------------------------------------
// K1 (MFMA): v-projection + fused softmax Gram. 128-n tiles (round-7 tiling,
// proven traffic profile) but 512-thread blocks: same 2 blocks/CU LDS cap now
// gives 16 waves/CU (was 8). Single-barrier double-buffered K-loop (2-phase):
// next tile's global_load_lds (Wv) + xT register loads are ISSUED before the
// MFMA phase and drained only by the post-MFMA barrier — staging latency
// overlaps compute. Each wave: acc[4][2] (64m x 32n). Max-free softmax stats:
// cs[n] block-local; rs[m] partials atomicAdd'd. Utilde = exp(v)*rsqrt(cs)
// hi/lo-bf16 staged to XOR-granule LDS (reusing the dbuf pool); Gram partial
// G = U^T U (hi*hi+hi*lo+lo*hi on the matrix pipe) written to Ap[nt].
// ---------------------------------------------------------------------------
__global__ __launch_bounds__(512, 4) void k_proj_v(
    const unsigned short* __restrict__ Wv,
    const unsigned short* __restrict__ xT,
    const float* __restrict__ b_v,
    float* __restrict__ Ap, float* __restrict__ rs) {
  __shared__ us8 pool[4][8 * 128];     // 64 KB: A0,A1,B0,B1 dbuf / Gram H+L
  __shared__ float cs_lds[2][128];     // column-sum partials (two m-halves)
  const int b = blockIdx.y;
  const int nt = blockIdx.x;
  const int t = threadIdx.x;           // 0..511
  const int wave = t >> 6, lane = t & 63;
  const int quad = lane >> 4, l16 = lane & 15;
  const int wm = (wave & 1) * 64;      // m-half
  const int wq = wave >> 1;            // n-quarter (K) / col-quarter (Gram)
  const int wn = wq * 32;
  f32x4 acc[4][2] = {};
  const unsigned short* xb = xT + ((size_t)b * Nn + nt * 128) * Cn;

  // prologue: stage tile 0 into buffers 0
  uint4 rB[2];
#pragma unroll
  for (int p = 0; p < 2; ++p) {
    int s = p * 512 + t;               // granule: row = s&127, g = s>>7
    rB[p] = *(const uint4*)&xb[(size_t)(s & 127) * Cn + (s >> 7) * 8];
    gload_lds16(&Wv[(size_t)(s & 127) * Cn + (s >> 7) * 8],
                &((unsigned short*)pool[0])[(size_t)s * 8]);
  }
#pragma unroll
  for (int p = 0; p < 2; ++p) {
    int s = p * 512 + t;
    *(uint4*)&((unsigned short*)pool[2])[(size_t)s * 8] = rB[p];
  }
  __syncthreads();

#pragma unroll
  for (int tt = 0; tt < 4; ++tt) {     // k0 = tt*64; cur buffer = tt&1
    const int cur = tt & 1;
    unsigned short* bufAc = (unsigned short*)pool[cur];
    unsigned short* bufBc = (unsigned short*)pool[2 + cur];
    if (tt < 3) {                      // issue next tile early (overlaps MFMA)
      int k1 = (tt + 1) * 64;
#pragma unroll
      for (int p = 0; p < 2; ++p) {
        int s = p * 512 + t;
        rB[p] = *(const uint4*)&xb[(size_t)(s & 127) * Cn + k1 + (s >> 7) * 8];
        gload_lds16(&Wv[(size_t)(s & 127) * Cn + k1 + (s >> 7) * 8],
                    &((unsigned short*)pool[cur ^ 1])[(size_t)s * 8]);
      }
    }
#pragma unroll
    for (int ss = 0; ss < 2; ++ss) {   // two k-steps of 32
      int g4 = ss * 4 + quad;
      bf16x8 af[4], bfr[2];
#pragma unroll
      for (int i = 0; i < 4; ++i)
        af[i] = *(const bf16x8*)&bufAc[(size_t)(g4 * 128 + wm + i * 16 + l16) * 8];
#pragma unroll
      for (int j = 0; j < 2; ++j)
        bfr[j] = *(const bf16x8*)&bufBc[(size_t)(g4 * 128 + wn + j * 16 + l16) * 8];
#pragma unroll
      for (int i = 0; i < 4; ++i)
#pragma unroll
        for (int j = 0; j < 2; ++j)
          acc[i][j] = __builtin_amdgcn_mfma_f32_16x16x32_bf16(af[i], bfr[j], acc[i][j], 0, 0, 0);
    }
    if (tt < 3) {                      // write-late: rB arrived under MFMA
#pragma unroll
      for (int p = 0; p < 2; ++p) {
        int s = p * 512 + t;
        *(uint4*)&((unsigned short*)pool[2 + (cur ^ 1)])[(size_t)s * 8] = rB[p];
      }
    }
    __syncthreads();                   // drains next-tile gloads AFTER compute
  }

  // ---- e = exp(v + b_v) in place ----
#pragma unroll
  for (int i = 0; i < 4; ++i) {
#pragma unroll
    for (int r = 0; r < 4; ++r) {
      float bi = b_v[wm + i * 16 + quad * 4 + r];
#pragma unroll
      for (int j = 0; j < 2; ++j)
        acc[i][j][r] = __expf(acc[i][j][r] + bi);
    }
  }

  // Row-sum partials (this wave's 32 n) -> atomicAdd rs[b,m]
#pragma unroll
  for (int i = 0; i < 4; ++i) {
#pragma unroll
    for (int r = 0; r < 4; ++r) {
      float s = acc[i][0][r] + acc[i][1][r];
      s += __shfl_xor(s, 1); s += __shfl_xor(s, 2);
      s += __shfl_xor(s, 4); s += __shfl_xor(s, 8);
      if (l16 == 0)
        atomicAdd(&rs[b * Mn + wm + i * 16 + quad * 4 + r], s);
    }
  }

  // Column sums cs[n] over ALL 128 m: quad-reduce gives this wave's 64-m
  // partial; LDS combines the two m-halves (waves 2q and 2q+1 share n-range).
  float csj[2];
#pragma unroll
  for (int j = 0; j < 2; ++j) {
    float c = 0.f;
#pragma unroll
    for (int i = 0; i < 4; ++i)
#pragma unroll
      for (int r = 0; r < 4; ++r) c += acc[i][j][r];
    c += __shfl_xor(c, 16);
    c += __shfl_xor(c, 32);
    csj[j] = c;
  }
  if (quad == 0) {
#pragma unroll
    for (int j = 0; j < 2; ++j) cs_lds[wave & 1][wn + j * 16 + l16] = csj[j];
  }
  __syncthreads();   // also: K-loop LDS reads done -> safe to overwrite pool

  float rinv[2];
#pragma unroll
  for (int j = 0; j < 2; ++j) {
    int nl = wn + j * 16 + l16;
    rinv[j] = rsqrtf(cs_lds[0][nl] + cs_lds[1][nl]);
  }

  // Stage Utilde hi/lo into XOR-granule LDS: granule g = n/8 (16 of them),
  // slot = g*128 + (m^g), halfword = n&7.
  unsigned short* Hs = (unsigned short*)pool;            // 32 KB (16*128 us8)
  unsigned short* Ls = Hs + 16 * 128 * 8;                // 32 KB
#pragma unroll
  for (int i = 0; i < 4; ++i) {
#pragma unroll
    for (int r = 0; r < 4; ++r) {
      int m = wm + i * 16 + quad * 4 + r;
#pragma unroll
      for (int j = 0; j < 2; ++j) {
        int nl = wn + j * 16 + l16;
        float u = acc[i][j][r] * rinv[j];
        unsigned short h = f2bf(u);
        union { unsigned int q; float f; } hf{(unsigned int)h << 16};
        int idx = ((nl >> 3) * 128 + (m ^ (nl >> 3))) * 8 + (nl & 7);
        Hs[idx] = h;
        Ls[idx] = f2bf(u - hf.f);
      }
    }
  }
  __syncthreads();

  // Gram MFMA: G[m][k] += sum_n U[n][m]*U[n][k], hi/lo 3-product scheme.
  // Wave covers rows wm..wm+63 x cols wk..wk+31; contraction = 128 n.
  const bf16x8* Hv = (const bf16x8*)pool;
  const bf16x8* Lv = Hv + 16 * 128;
  const int wk = wq * 32;
#pragma unroll
  for (int i = 0; i < 4; ++i)
#pragma unroll
    for (int j = 0; j < 2; ++j) acc[i][j] = (f32x4){0.f, 0.f, 0.f, 0.f};
#pragma unroll
  for (int sg = 0; sg < 4; ++sg) {
    int g = sg * 4 + quad;
    bf16x8 hA[4], lA[4], hB[2], lB[2];
#pragma unroll
    for (int i = 0; i < 4; ++i) {
      int mi = wm + i * 16 + l16;
      hA[i] = Hv[g * 128 + (mi ^ g)];
      lA[i] = Lv[g * 128 + (mi ^ g)];
    }
#pragma unroll
    for (int j = 0; j < 2; ++j) {
      int ki = wk + j * 16 + l16;
      hB[j] = Hv[g * 128 + (ki ^ g)];
      lB[j] = Lv[g * 128 + (ki ^ g)];
    }
#pragma unroll
    for (int i = 0; i < 4; ++i)
#pragma unroll
      for (int j = 0; j < 2; ++j) {
        acc[i][j] = __builtin_amdgcn_mfma_f32_16x16x32_bf16(hA[i], hB[j], acc[i][j], 0, 0, 0);
        acc[i][j] = __builtin_amdgcn_mfma_f32_16x16x32_bf16(hA[i], lB[j], acc[i][j], 0, 0, 0);
        acc[i][j] = __builtin_amdgcn_mfma_f32_16x16x32_bf16(lA[i], hB[j], acc[i][j], 0, 0, 0);
      }
  }

  float* Apb = Ap + ((size_t)nt * Bn + b) * (Mn * Mn);
#pragma unroll
  for (int i = 0; i < 4; ++i) {
#pragma unroll
    for (int r = 0; r < 4; ++r) {
      int m = wm + i * 16 + quad * 4 + r;
      float* row = &Apb[(size_t)m * Mn];
#pragma unroll
      for (int j = 0; j < 2; ++j)
        row[wk + j * 16 + l16] = acc[i][j][r];
    }
  }
}

// ---------------------------------------------------------------------------
// K2: A[b][m][k] = (1/rs[b][m]) * sum_s Ap[s][b][m][k]
// ---------------------------------------------------------------------------
__global__ __launch_bounds__(256) void k_reduceA(
    const float* __restrict__ Ap, const float* __restrict__ rs,
    float* __restrict__ A, int S) {
  int tid = blockIdx.x * 256 + threadIdx.x;           // over Bn*Mn*Mn/4
  int idx4 = tid * 4;
  int b = idx4 / (Mn * Mn);
  int off = idx4 - b * (Mn * Mn);
  float4 s = {0.f, 0.f, 0.f, 0.f};
  for (int s0 = 0; s0 < S; ++s0) {
    float4 p = *(const float4*)&Ap[((size_t)s0 * Bn + b) * (Mn * Mn) + off];
    s.x += p.x; s.y += p.y; s.z += p.z; s.w += p.w;
  }
  float sc = 1.0f / rs[b * Mn + (off >> 7)];   // row m scale
  s.x *= sc; s.y *= sc; s.z *= sc; s.w *= sc;
  *(float4*)&A[idx4] = s;
}

// ---------------------------------------------------------------------------
// K3: W2bf[b,c,m] = bf16( sum_k w_c[c,k] * A[b,m,k] )  (m-contiguous)
// ---------------------------------------------------------------------------
__global__ __launch_bounds__(256) void k_w2(
    const float* __restrict__ w_c, const float* __restrict__ A,
    unsigned short* __restrict__ W2bf) {
  __shared__ float As[64][68];   // [k][m-local]
  __shared__ float wcs[64][68];  // [k][c-local]
  const int b = blockIdx.z;
  const int m0 = blockIdx.x * 64;
  const int c0 = blockIdx.y * 64;
  const int t = threadIdx.x;
  const int tc = (t >> 4) * 4, tmm = (t & 15) * 4;
  float acc[4][4] = {};
  for (int k0 = 0; k0 < Mn; k0 += 64) {
    int r = t >> 2;             // 0..63
    int k4 = (t & 3) * 4;
#pragma unroll
    for (int p = 0; p < 4; ++p) {
      int k = k4 + p * 16;
      float4 a4 = *(const float4*)&A[((size_t)(b * Mn + m0 + r)) * Mn + k0 + k];
      As[k + 0][r] = a4.x; As[k + 1][r] = a4.y; As[k + 2][r] = a4.z; As[k + 3][r] = a4.w;
      float4 w4 = *(const float4*)&w_c[(size_t)(c0 + r) * Mn + k0 + k];
      wcs[k + 0][r] = w4.x; wcs[k + 1][r] = w4.y; wcs[k + 2][r] = w4.z; wcs[k + 3][r] = w4.w;
    }
    __syncthreads();
#pragma unroll
    for (int kk = 0; kk < 64; ++kk) {
      float4 w4 = *(const float4*)&wcs[kk][tc];
      float4 a4 = *(const float4*)&As[kk][tmm];
      float w[4] = {w4.x, w4.y, w4.z, w4.w};
      float a[4] = {a4.x, a4.y, a4.z, a4.w};
#pragma unroll
      for (int i = 0; i < 4; ++i)
#pragma unroll
        for (int jj = 0; jj < 4; ++jj) acc[i][jj] = fmaf(w[i], a[jj], acc[i][jj]);
    }
    __syncthreads();
  }
#pragma unroll
  for (int i = 0; i < 4; ++i) {
    us4 g4 = {f2bf(acc[i][0]), f2bf(acc[i][1]), f2bf(acc[i][2]), f2bf(acc[i][3])};
    *(us4*)&W2bf[((size_t)(b * Cn + c0 + tc + i)) * Mn + m0 + tmm] = g4;
  }
}

// ---------------------------------------------------------------------------
// K4 (MFMA): WW[b][c][c'] = bf16( sum_m W2bf[b,c,m] * woT[c',m] )  (= W2*W_o)
// Also (c'-tile 0 blocks): bb[b][c] = sum_m W2[c,m]*b_o[m] + b_c[c].
// ---------------------------------------------------------------------------
__global__ __launch_bounds__(256) void k_ww(
    const unsigned short* __restrict__ W2bf, const unsigned short* __restrict__ woT,
    const float* __restrict__ b_o, const float* __restrict__ b_c,
    unsigned short* __restrict__ WW, float* __restrict__ bb) {
  __shared__ us8 ldsA[128 * 16];  // 32 KB: W2 c-rows   [row][granule^]
  __shared__ us8 ldsB[128 * 16];  // 32 KB: woT c'-rows
  __shared__ float bo_lds[128];
  const int b = blockIdx.z;
  const int c_t = blockIdx.y * 128;
  const int cp_t = blockIdx.x * 128;
  const int t = threadIdx.x;
  const int wave = t >> 6, lane = t & 63;
  const int quad = lane >> 4, l16 = lane & 15;
  const int wc = (wave & 1) * 64, wp = (wave >> 1) * 64;
  const unsigned short* W2b = W2bf + ((size_t)b * Cn + c_t) * Mn;
  const unsigned short* woB = woT + (size_t)cp_t * Mn;

#pragma unroll
  for (int p = 0; p < 8; ++p) {
    int s = p * 256 + t;
    int row = s >> 4, g = s & 15;
    int slot = row * 16 + (g ^ (row & 15));
    ldsA[slot] = *(const us8*)&W2b[(size_t)row * Mn + g * 8];
    ldsB[slot] = *(const us8*)&woB[(size_t)row * Mn + g * 8];
  }
  if (blockIdx.x == 0 && t < 128) bo_lds[t] = b_o[t];
  __syncthreads();

  f32x4 acc[4][4] = {};
#pragma unroll
  for (int s = 0; s < 4; ++s) {
    int gq = s * 4 + quad;
    int xo = gq ^ l16;
    bf16x8 af[4], bfr[4];
#pragma unroll
    for (int i = 0; i < 4; ++i)
      af[i] = *(const bf16x8*)&ldsA[(wc + i * 16 + l16) * 16 + xo];
#pragma unroll
    for (int j = 0; j < 4; ++j)
      bfr[j] = *(const bf16x8*)&ldsB[(wp + j * 16 + l16) * 16 + xo];
#pragma unroll
    for (int i = 0; i < 4; ++i)
#pragma unroll
      for (int j = 0; j < 4; ++j)
        acc[i][j] = __builtin_amdgcn_mfma_f32_16x16x32_bf16(af[i], bfr[j], acc[i][j], 0, 0, 0);
  }

#pragma unroll
  for (int i = 0; i < 4; ++i) {
#pragma unroll
    for (int r = 0; r < 4; ++r) {
      int c = c_t + wc + i * 16 + quad * 4 + r;
      unsigned short* row = &WW[((size_t)b * Cn + c) * Cn + cp_t];
#pragma unroll
      for (int j = 0; j < 4; ++j)
        row[wp + j * 16 + l16] = f2bf(acc[i][j][r]);
    }
  }

  if (blockIdx.x == 0 && t < 128) {   // bias: dot(W2[c,:], b_o) + b_c
    float s = 0.f;
#pragma unroll
    for (int g = 0; g < 16; ++g) {
      us8 h = ldsA[t * 16 + (g ^ (t & 15))];
#pragma unroll
      for (int e = 0; e < 8; ++e) {
        union { unsigned int u; float f; } cv{(unsigned int)h[e] << 16};
        s = fmaf(cv.f, bo_lds[g * 8 + e], s);
      }
    }
    bb[b * Cn + c_t + t] = s + b_c[c_t + t];
  }
}

// ---------------------------------------------------------------------------
// K5 (MFMA): out[b,c,n] = gamma*relu(sum_{c'} WW[c,c']*xT[n,c'] + bb[c]) + x
// Tile 128c x 128n, K=256 in two staged halves. Staging via global_load_lds
// w=16 with PRE-SWIZZLED global source (granule g' = g ^ (row&15)) so the
// LDS dest stays linear while reads keep the proven XOR layout (2-way free).
// XCD-aware bijective block swizzle: each XCD gets 2 contiguous batches so
// its 4 MB L2 holds that batch-pair's xT panels + WW.
// ---------------------------------------------------------------------------
__global__ __launch_bounds__(256) void k_final_mfma(
    const unsigned short* __restrict__ WW, const unsigned short* __restrict__ xT,
    const float* __restrict__ x, const float* __restrict__ bb,
    const float* __restrict__ gamma, float* __restrict__ out) {
  __shared__ us8 ldsA[128 * 16];  // 32 KB: WW c-rows (one K-half)
  __shared__ us8 ldsB[128 * 16];  // 32 KB: xT n-rows
  // flat grid = 32 x 2 x 16 = 1024; 1024 % 8 == 0 -> simple bijective swizzle
  const int flat = blockIdx.x + 32 * blockIdx.y + 64 * (int)blockIdx.z;
  const int swz = (flat & 7) * 128 + (flat >> 3);
  const int n_t = (swz & 31) * 128;
  const int c_t = ((swz >> 5) & 1) * 128;
  const int b = swz >> 6;
  const int t = threadIdx.x;
  const int wave = t >> 6, lane = t & 63;
  const int quad = lane >> 4, l16 = lane & 15;
  const int wc = (wave & 1) * 64, wn = (wave >> 1) * 64;
  const unsigned short* WWb = WW + ((size_t)b * Cn + c_t) * Cn;
  const unsigned short* xTb = xT + ((size_t)b * Nn + n_t) * Cn;
  unsigned short* ldsAu = (unsigned short*)ldsA;
  unsigned short* ldsBu = (unsigned short*)ldsB;

  f32x4 acc[4][4] = {};
  for (int k0 = 0; k0 < Cn; k0 += 128) {
#pragma unroll
    for (int p = 0; p < 8; ++p) {   // 2048 granules per operand, 8/thread
      int s = p * 256 + t;
      int row = s >> 4, g = s & 15;
      int gsw = g ^ (row & 15);     // pre-swizzled source granule
      gload_lds16(&WWb[(size_t)row * Cn + k0 + gsw * 8], &ldsAu[(size_t)s * 8]);
      gload_lds16(&xTb[(size_t)row * Cn + k0 + gsw * 8], &ldsBu[(size_t)s * 8]);
    }
    __syncthreads();
#pragma unroll
    for (int s = 0; s < 4; ++s) {
      int gq = s * 4 + quad;
      int xo = gq ^ l16;
      bf16x8 af[4], bfr[4];
#pragma unroll
      for (int i = 0; i < 4; ++i)
        af[i] = *(const bf16x8*)&ldsA[(wc + i * 16 + l16) * 16 + xo];
#pragma unroll
      for (int j = 0; j < 4; ++j)
        bfr[j] = *(const bf16x8*)&ldsB[(wn + j * 16 + l16) * 16 + xo];
#pragma unroll
      for (int i = 0; i < 4; ++i)
#pragma unroll
        for (int j = 0; j < 4; ++j)
          acc[i][j] = __builtin_amdgcn_mfma_f32_16x16x32_bf16(af[i], bfr[j], acc[i][j], 0, 0, 0);
    }
    __syncthreads();
  }

  float g = gamma[0];
#pragma unroll
  for (int i = 0; i < 4; ++i) {
#pragma unroll
    for (int r = 0; r < 4; ++r) {
      int c = c_t + wc + i * 16 + quad * 4 + r;
      float bias = bb[b * Cn + c];
      const float* xr = &x[((size_t)b * Cn + c) * Nn + n_t];
      float* orow = &out[((size_t)b * Cn + c) * Nn + n_t];
#pragma unroll
      for (int j = 0; j < 4; ++j) {
        int n = wn + j * 16 + l16;
        orow[n] = g * fmaxf(acc[i][j][r] + bias, 0.f) + xr[n];
      }
    }
  }
}

// ---------------------------------------------------------------------------
extern "C" void kernel_launch(void* const* d_in, const int* in_sizes, int n_in,
                              void* d_out, int out_size, void* d_ws, size_t ws_size,
                              hipStream_t stream) {
  const float* x   = (const float*)d_in[0];
  const float* w_o = (const float*)d_in[1];
  const float* b_o = (const float*)d_in[2];
  const float* w_v = (const float*)d_in[3];
  const float* b_v = (const float*)d_in[4];
  const float* w_c = (const float*)d_in[5];
  const float* b_c = (const float*)d_in[6];
  const float* gm  = (const float*)d_in[7];

  constexpr int S = Nn / 128;                      // 32 Gram slices
  float* ws = (float*)d_ws;
  float* rs = ws;                                  // B*M fp32 (atomic)
  float* bb = rs + Bn * Mn;                        // B*C fp32
  float* A  = bb + Bn * Cn;                        // B*M*M fp32
  float* Ap = A + (size_t)Bn * Mn * Mn;            // S*B*M*M fp32
  unsigned short* WW   = (unsigned short*)(Ap + (size_t)S * Bn * Mn * Mn); // B*C*C bf16
  unsigned short* W2bf = WW + (size_t)Bn * Cn * Cn;                 // B*C*M bf16
  unsigned short* xT   = W2bf + (size_t)Bn * Cn * Mn;               // B*N*C bf16
  unsigned short* Wv   = xT + (size_t)Bn * Nn * Cn;                 // M*C bf16
  unsigned short* woT  = Wv + (size_t)Mn * Cn;                      // C*M bf16

  k_prep<<<dim3(Nn / 64, 2, Bn), 256, 0, stream>>>(x, xT, w_o, w_v, Wv, woT, rs);
  k_proj_v<<<dim3(Nn / 128, Bn), 512, 0, stream>>>(Wv, xT, b_v, Ap, rs);
  k_reduceA<<<dim3(Bn * Mn * Mn / 1024), 256, 0, stream>>>(Ap, rs, A, S);
  k_w2<<<dim3(Mn / 64, Cn / 64, Bn), 256, 0, stream>>>(w_c, A, W2bf);
  k_ww<<<dim3(2, 2, Bn), 256, 0, stream>>>(W2bf, woT, b_o, b_c, WW, bb);
  k_final_mfma<<<dim3(Nn / 128, Cn / 128, Bn), 256, 0, stream>>>(WW, xT, x, bb, gm, (float*)d_out);
}